// Round 11
// baseline (177.307 us; speedup 1.0000x reference)
//
#include <hip/hip_runtime.h>
#include <hip/hip_bf16.h>

typedef __attribute__((ext_vector_type(8))) __bf16 bf16x8;
typedef __attribute__((ext_vector_type(4))) __bf16 bf16x4;
typedef __attribute__((ext_vector_type(4))) float  f32x4;
typedef __attribute__((ext_vector_type(4))) short  s16x4;

#define S_LEN 2048
#define D_DIM 1024
#define NH    16
#define GK    1024
#define GN    1024

__device__ __forceinline__ float fast_exp2(float x) {
#if __has_builtin(__builtin_amdgcn_exp2f)
  return __builtin_amdgcn_exp2f(x);
#else
  return exp2f(x);
#endif
}

// K=16 bf16 MFMA wrapper (builtin spelling differs across ROCm versions)
__device__ __forceinline__ f32x4 mfma16(bf16x4 a, bf16x4 b, f32x4 c) {
#if __has_builtin(__builtin_amdgcn_mfma_f32_16x16x16_bf16)
  return __builtin_amdgcn_mfma_f32_16x16x16_bf16(a, b, c, 0, 0, 0);
#else
  return __builtin_amdgcn_mfma_f32_16x16x16bf16_1k(
      __builtin_bit_cast(s16x4, a), __builtin_bit_cast(s16x4, b), c, 0, 0, 0);
#endif
}

// async global->LDS, 16B per lane; HW scatters to wave-uniform-base + lane*16
__device__ __forceinline__ void gld_lds16(const void* g, void* l) {
  __builtin_amdgcn_global_load_lds(
      (const __attribute__((address_space(1))) unsigned int*)g,
      (__attribute__((address_space(3))) unsigned int*)l, 16, 0, 0);
}

// ---------------- fused fp32 -> bf16 cast, grid-stride ----------------
__global__ __launch_bounds__(256) void cast_all(
    const float* __restrict__ x,  const float* __restrict__ wq, const float* __restrict__ wk,
    const float* __restrict__ wv, const float* __restrict__ wo,
    __bf16* __restrict__ xb, __bf16* __restrict__ wqb, __bf16* __restrict__ wkb,
    __bf16* __restrict__ wvb, __bf16* __restrict__ wob)
{
  const int NTOT = 2 << 20;                      // 2M float4 chunks
  for (int i = blockIdx.x * 256 + threadIdx.x; i < NTOT; i += 1024 * 256) {
    const float* s; __bf16* d; int off;
    if (i < (1 << 20)) { s = x; d = xb; off = i; }
    else {
      const int j = i - (1 << 20);
      const int r = j >> 18; off = j & ((1 << 18) - 1);
      s = (r == 0) ? wq : (r == 1) ? wk : (r == 2) ? wv : wo;
      d = (r == 0) ? wqb : (r == 1) ? wkb : (r == 2) ? wvb : wob;
    }
    float4 v = ((const float4*)s)[off];
    bf16x4 o = { (__bf16)v.x, (__bf16)v.y, (__bf16)v.z, (__bf16)v.w };
    ((bf16x4*)d)[off] = o;
  }
}

// ---------------- QKV GEMM 64x128, BK=64, XCD-partitioned (r0 proven) ----------
// mode 2 (V) writes LDS-order fragment layout per 64-key tile:
//   Vf[bh][kt][d][cp*8 + (kb&1)*4 + r], cp = ((ql<<1)|(kb>>1)) ^ (d&7)
//   where key = kb*16 + ql*4 + r. attn stages it LINEARLY (global src == LDS
//   order) and PV reads 2x b128 per (jb): conflict-free, contiguous per lane.
__global__ __launch_bounds__(256, 6) void gemm_qkv(
    const __bf16* __restrict__ A,
    const __bf16* __restrict__ W0, const __bf16* __restrict__ W1, const __bf16* __restrict__ W2,
    __bf16* __restrict__ C0, __bf16* __restrict__ C1, __bf16* __restrict__ VtOut)
{
  const int bid = blockIdx.x;
  const int e = bid & 7, mg = e >> 1, ng = e & 1;
  const int q = bid >> 3;              // 0..191
  const int mode = q % 3;
  const int t = q / 3;                 // 0..63
  const int m0 = (mg * 16 + (t & 15)) * 64;
  const int n0 = (ng * 4 + (t >> 4)) * 128;
  const __bf16* Wm = (mode == 0) ? W0 : (mode == 1) ? W1 : W2;

  __shared__ __align__(16) __bf16 As[64 * 64];    //  8 KB
  __shared__ __align__(16) __bf16 Bs[128 * 64];   // 16 KB

  const int tid  = threadIdx.x;
  const int lane = tid & 63;
  const int w    = tid >> 6;
  const int wr   = w >> 1, wc = w & 1;
  const int lm   = lane & 15, qd = lane >> 4;

  const __bf16* ap[2]; int loA[2];
  #pragma unroll
  for (int j = 0; j < 2; j++) {
    const int c = tid + 256 * j;
    const int r = c >> 3, cpos = c & 7;
    ap[j] = A + (size_t)(m0 + r) * GK + (cpos ^ (r & 7)) * 8;
    loA[j] = c * 8;
  }
  const __bf16* bp[4]; int loB[4];
  #pragma unroll
  for (int j = 0; j < 4; j++) {
    const int c = tid + 256 * j;
    const int r = c >> 3, cpos = c & 7;
    bp[j] = Wm + (size_t)(n0 + r) * GK + (cpos ^ (r & 7)) * 8;
    loB[j] = c * 8;
  }

  const int sw = lm & 7;

  f32x4 zero = {0.f, 0.f, 0.f, 0.f};
  f32x4 acc[2][4];
  #pragma unroll
  for (int i = 0; i < 2; i++)
    #pragma unroll
    for (int j = 0; j < 4; j++) acc[i][j] = zero;

  for (int k0 = 0; k0 < GK; k0 += 64) {
    #pragma unroll
    for (int j = 0; j < 2; j++) gld_lds16(ap[j] + k0, &As[loA[j]]);
    #pragma unroll
    for (int j = 0; j < 4; j++) gld_lds16(bp[j] + k0, &Bs[loB[j]]);
    __syncthreads();
    #pragma unroll
    for (int half = 0; half < 2; half++) {
      const int cph = ((qd + 4 * half) ^ sw) * 8;
      bf16x8 af[2], bfv[4];
      #pragma unroll
      for (int i = 0; i < 2; i++) af[i]  = *(const bf16x8*)&As[(wr * 32 + i * 16 + lm) * 64 + cph];
      #pragma unroll
      for (int j = 0; j < 4; j++) bfv[j] = *(const bf16x8*)&Bs[(wc * 64 + j * 16 + lm) * 64 + cph];
      #pragma unroll
      for (int i = 0; i < 2; i++)
        #pragma unroll
        for (int j = 0; j < 4; j++)
          acc[i][j] = __builtin_amdgcn_mfma_f32_16x16x32_bf16(af[i], bfv[j], acc[i][j], 0, 0, 0);
    }
    __syncthreads();
  }

  if (mode < 2) {
    __bf16* C = (mode == 0) ? C0 : C1;
    #pragma unroll
    for (int i = 0; i < 2; i++) {
      const int row = m0 + wr * 32 + i * 16 + qd * 4;
      #pragma unroll
      for (int j = 0; j < 4; j++) {
        const int col = n0 + wc * 64 + j * 16 + lm;
        #pragma unroll
        for (int r = 0; r < 4; r++)
          C[(size_t)(row + r) * GN + col] = (__bf16)acc[i][j][r];
      }
    }
  } else {
    #pragma unroll
    for (int i = 0; i < 2; i++) {
      const int row = m0 + wr * 32 + i * 16 + qd * 4;    // token (4 consecutive)
      const int b = row >> 11, s = row & (S_LEN - 1);
      const int kt = s >> 6;
      const int key = s & 63;                            // key&3 == 0
      const int kb = (key >> 4) & 3, ql = (key >> 2) & 3;
      #pragma unroll
      for (int j = 0; j < 4; j++) {
        const int col = n0 + wc * 64 + j * 16 + lm;      // vdim
        const int h = col >> 6, d = col & 63;
        const int cp = ((ql << 1) | (kb >> 1)) ^ (d & 7);
        bf16x4 o = { (__bf16)acc[i][j][0], (__bf16)acc[i][j][1],
                     (__bf16)acc[i][j][2], (__bf16)acc[i][j][3] };
        const size_t idx =
            (((size_t)((b * NH + h) * 32 + kt)) * 64 + d) * 64 + cp * 8 + (kb & 1) * 4;
        *(bf16x4*)(VtOut + idx) = o;
      }
    }
  }
}

// ---------------- out-proj GEMM 64x128, BK=64, double-buffered (fp32 out) --------
// grid 512 = 2 blocks/CU (grid-limited): no TLP to hide staging, so prefetch
// next tile BEFORE compute and use ONE barrier per K-step (it drains the
// prefetch and protects buf reuse) -- same proven pattern as attn's loop.
__global__ __launch_bounds__(256, 2) void gemm_out64(
    const __bf16* __restrict__ A, const __bf16* __restrict__ Wm, float* __restrict__ C)
{
  const int bid = blockIdx.x;          // 512
  const int e = bid & 7, mg = e >> 1, ng = e & 1;
  const int q = bid >> 3;              // 0..63
  const int m0 = (mg * 16 + (q & 15)) * 64;
  const int n0 = (ng * 4 + (q >> 4)) * 128;

  __shared__ __align__(16) __bf16 As[2][64 * 64];    // 16 KB
  __shared__ __align__(16) __bf16 Bs[2][128 * 64];   // 32 KB

  const int tid  = threadIdx.x;
  const int lane = tid & 63;
  const int w    = tid >> 6;
  const int wr   = w >> 1, wc = w & 1;
  const int lm   = lane & 15, qd = lane >> 4;

  const __bf16* ap[2]; int loA[2];
  #pragma unroll
  for (int j = 0; j < 2; j++) {
    const int c = tid + 256 * j;
    const int r = c >> 3, cpos = c & 7;
    ap[j] = A + (size_t)(m0 + r) * GK + (cpos ^ (r & 7)) * 8;
    loA[j] = c * 8;
  }
  const __bf16* bp[4]; int loB[4];
  #pragma unroll
  for (int j = 0; j < 4; j++) {
    const int c = tid + 256 * j;
    const int r = c >> 3, cpos = c & 7;
    bp[j] = Wm + (size_t)(n0 + r) * GK + (cpos ^ (r & 7)) * 8;
    loB[j] = c * 8;
  }

  const int sw = lm & 7;

  auto stage = [&](int buf, int k0) {
    #pragma unroll
    for (int j = 0; j < 2; j++) gld_lds16(ap[j] + k0, &As[buf][loA[j]]);
    #pragma unroll
    for (int j = 0; j < 4; j++) gld_lds16(bp[j] + k0, &Bs[buf][loB[j]]);
  };

  f32x4 zero = {0.f, 0.f, 0.f, 0.f};
  f32x4 acc[2][4];
  #pragma unroll
  for (int i = 0; i < 2; i++)
    #pragma unroll
    for (int j = 0; j < 4; j++) acc[i][j] = zero;

  stage(0, 0);

  for (int kt = 0; kt < 16; ++kt) {
    const int cur = kt & 1;
    __syncthreads();                   // buf[cur] staged; all done reading buf[cur^1]
    if (kt < 15) stage(cur ^ 1, (kt + 1) * 64);
    #pragma unroll
    for (int half = 0; half < 2; half++) {
      const int cph = ((qd + 4 * half) ^ sw) * 8;
      bf16x8 af[2], bfv[4];
      #pragma unroll
      for (int i = 0; i < 2; i++) af[i]  = *(const bf16x8*)&As[cur][(wr * 32 + i * 16 + lm) * 64 + cph];
      #pragma unroll
      for (int j = 0; j < 4; j++) bfv[j] = *(const bf16x8*)&Bs[cur][(wc * 64 + j * 16 + lm) * 64 + cph];
      #pragma unroll
      for (int i = 0; i < 2; i++)
        #pragma unroll
        for (int j = 0; j < 4; j++)
          acc[i][j] = __builtin_amdgcn_mfma_f32_16x16x32_bf16(af[i], bfv[j], acc[i][j], 0, 0, 0);
    }
  }

  #pragma unroll
  for (int i = 0; i < 2; i++) {
    const int row = m0 + wr * 32 + i * 16 + qd * 4;
    #pragma unroll
    for (int j = 0; j < 4; j++) {
      const int col = n0 + wc * 64 + j * 16 + lm;
      #pragma unroll
      for (int r = 0; r < 4; r++)
        C[(size_t)(row + r) * GN + col] = acc[i][j][r];
    }
  }
}

// ---------------- RMSNorm + RoPE + head split, wave-per-row (no LDS/barrier) -----
__global__ __launch_bounds__(256) void norm_rope(
    const __bf16* __restrict__ Qf, const __bf16* __restrict__ Kf,
    const float* __restrict__ gain, const int* __restrict__ positions,
    const int* __restrict__ theta_p,
    __bf16* __restrict__ Qh, __bf16* __restrict__ Kh)
{
  const int t = threadIdx.x;
  const int w = t >> 6, lane = t & 63;
  const int row = blockIdx.x * 4 + w;             // b*S + s
  const int s = row & (S_LEN - 1), b = row >> 11;
  const int d0 = lane * 16;

  const bf16x8 qv0 = *(const bf16x8*)(Qf + (size_t)row * D_DIM + d0);
  const bf16x8 qv1 = *(const bf16x8*)(Qf + (size_t)row * D_DIM + d0 + 8);
  const bf16x8 kv0 = *(const bf16x8*)(Kf + (size_t)row * D_DIM + d0);
  const bf16x8 kv1 = *(const bf16x8*)(Kf + (size_t)row * D_DIM + d0 + 8);

  float q[16], k[16];
  #pragma unroll
  for (int j = 0; j < 8; j++) {
    q[j] = (float)qv0[j]; q[8 + j] = (float)qv1[j];
    k[j] = (float)kv0[j]; k[8 + j] = (float)kv1[j];
  }
  float sq = 0.f, sk = 0.f;
  #pragma unroll
  for (int j = 0; j < 16; j++) { sq += q[j] * q[j]; sk += k[j] * k[j]; }
  #pragma unroll
  for (int off = 32; off; off >>= 1) { sq += __shfl_xor(sq, off); sk += __shfl_xor(sk, off); }

  const float SC2 = 0.125f * 1.44269504089f;
  const float invq = rsqrtf(sq * (1.0f / 1024.0f) + 1e-5f) * SC2;   // fold score scale
  const float invk = rsqrtf(sk * (1.0f / 1024.0f) + 1e-5f);

  float g[16];
  #pragma unroll
  for (int j = 0; j < 4; j++) {
    const float4 gv = *(const float4*)(gain + d0 + j * 4);
    g[4 * j] = gv.x; g[4 * j + 1] = gv.y; g[4 * j + 2] = gv.z; g[4 * j + 3] = gv.w;
  }

  const float pos  = (float)positions[s];
  const float lg32 = __log2f((float)theta_p[0]) * (1.0f / 32.0f);
  const int h = lane >> 2, idx0 = (lane & 3) * 16;

  bf16x8 qw0, qw1, kw0, kw1;
  #pragma unroll
  for (int pp = 0; pp < 8; pp++) {
    const int p = (lane & 3) * 8 + pp;
    const float f = fast_exp2(-(float)p * lg32);
    float sn, cs;
    __sincosf(pos * f, &sn, &cs);
    const float qe = q[2 * pp] * invq * g[2 * pp];
    const float qo = q[2 * pp + 1] * invq * g[2 * pp + 1];
    const float ke = k[2 * pp] * invk * g[2 * pp];
    const float ko = k[2 * pp + 1] * invk * g[2 * pp + 1];
    const __bf16 qre = (__bf16)(qe * cs - qo * sn);
    const __bf16 qro = (__bf16)(qo * cs + qe * sn);
    const __bf16 kre = (__bf16)(ke * cs - ko * sn);
    const __bf16 kro = (__bf16)(ko * cs + ke * sn);
    if (pp < 4) { qw0[2 * pp] = qre; qw0[2 * pp + 1] = qro;
                  kw0[2 * pp] = kre; kw0[2 * pp + 1] = kro; }
    else        { qw1[2 * (pp - 4)] = qre; qw1[2 * (pp - 4) + 1] = qro;
                  kw1[2 * (pp - 4)] = kre; kw1[2 * (pp - 4) + 1] = kro; }
  }

  const size_t obase = ((size_t)((b * NH + h) * S_LEN + s)) * 64 + idx0;
  *(bf16x8*)(Qh + obase)     = qw0;
  *(bf16x8*)(Qh + obase + 8) = qw1;
  *(bf16x8*)(Kh + obase)     = kw0;
  *(bf16x8*)(Kh + obase + 8) = kw1;
}

// ---------------- causal flash attention, S^T formulation (r10 proven) -----------
// K LDS-staged (swizzled, dbuf). V stored in LDS-fragment order by gemm_qkv:
// staging is a LINEAR 8KB copy per tile, and PV reads 2x ds_read_b128 per jb
// (conflict-free) instead of 4x ds_read_b64. Same waves, barriers, masking.
__global__ __launch_bounds__(256) void attn_fwd(
    const __bf16* __restrict__ Qh, const __bf16* __restrict__ Kh,
    const __bf16* __restrict__ Vf, __bf16* __restrict__ Ob)
{
  const int bid = blockIdx.x;
  const int g   = bid >> 5, gj = g & 7, gs = g >> 3;
  const int qt  = (gs == 0) ? 31 - gj : (gs == 1) ? gj : (gs == 2) ? 23 - gj : 8 + gj;
  const int rr  = bid & 31;
  const int bh  = (rr & 7) * 4 + (rr >> 3);      // same-bh blocks -> same bid%8 (XCD)
  const int tid = threadIdx.x, lane = tid & 63, w = tid >> 6;
  const int lm = lane & 15, qd = lane >> 4;

  __shared__ __align__(16) __bf16 smem[8192 + 8192];   // 32768 B
  __bf16* Ks = smem;                 // [2][4096]
  __bf16* Vs = smem + 8192;          // [2][4096]

  const int row0 = qt * 64 + w * 16;
  const int qglob = row0 + lm;                   // this lane's query row
  const size_t qbase = (size_t)bh * S_LEN * 64;
  const bf16x8 aq0 = *(const bf16x8*)(Qh + qbase + (size_t)qglob * 64 + qd * 8);
  const bf16x8 aq1 = *(const bf16x8*)(Qh + qbase + (size_t)qglob * 64 + 32 + qd * 8);

  const __bf16* Kb  = Kh + (size_t)bh * S_LEN * 64;
  const __bf16* Vbh = Vf + (size_t)bh * 32 * 4096;     // [kt][4096] frag-order tiles
  const int c0 = tid, c1 = 256 + tid;
  const int kr0 = c0 >> 3, kr1 = c1 >> 3;
  const int kg0 = ((c0 & 7) ^ (kr0 & 7)) * 8;
  const int kg1 = ((c1 & 7) ^ (kr1 & 7)) * 8;
  const int cpA = (qd ^ (lm & 7)) * 8;
  const int cpB = cpA ^ 32;

  auto stage = [&](int buf, int k0) {
    __bf16* Kd = Ks + buf * 4096;
    __bf16* Vd = Vs + buf * 4096;
    gld_lds16(Kb + (size_t)(k0 + kr0) * 64 + kg0, &Kd[c0 * 8]);
    gld_lds16(Kb + (size_t)(k0 + kr1) * 64 + kg1, &Kd[c1 * 8]);
    const __bf16* Vt_ = Vbh + (size_t)(k0 >> 6) * 4096;
    gld_lds16(Vt_ + c0 * 8, &Vd[c0 * 8]);
    gld_lds16(Vt_ + c1 * 8, &Vd[c1 * 8]);
  };

  f32x4 zero = {0.f, 0.f, 0.f, 0.f};
  f32x4 lacc = zero;                 // all 4 regs hold l[q=lm]
  f32x4 o[4];                        // o[jb][r] = O^T[d = jb*16+qd*4+r][q=lm]
  #pragma unroll
  for (int jb = 0; jb < 4; jb++) o[jb] = zero;

  bf16x4 ones4;
  #pragma unroll
  for (int i = 0; i < 4; i++) ones4[i] = (__bf16)1.0f;

  stage(0, 0);

  for (int kt = 0; kt <= qt; ++kt) {
    const int cur = kt & 1;
    __syncthreads();                 // buf[cur] staged; buf[cur^1] free
    if (kt < qt) stage(cur ^ 1, (kt + 1) * 64);

    const __bf16* Kc = Ks + cur * 4096;
    const __bf16* Vc = Vs + cur * 4096;
    const int k0 = kt * 64;
    const bool diag = (kt == qt);

    bf16x4 pfrag[4];
    #pragma unroll
    for (int kb = 0; kb < 4; kb++) {
      const int krow = (kb * 16 + lm) * 64;
      const bf16x8 ak0 = *(const bf16x8*)&Kc[krow + cpA];
      const bf16x8 ak1 = *(const bf16x8*)&Kc[krow + cpB];
      f32x4 sc = zero;                                   // S^T: A=K, B=Q
      sc = __builtin_amdgcn_mfma_f32_16x16x32_bf16(ak0, aq0, sc, 0, 0, 0);
      sc = __builtin_amdgcn_mfma_f32_16x16x32_bf16(ak1, aq1, sc, 0, 0, 0);
      float p[4];
      if (diag) {
        const int keyb = k0 + kb * 16 + qd * 4;
        #pragma unroll
        for (int r = 0; r < 4; r++)
          p[r] = (keyb + r <= qglob) ? fast_exp2(sc[r]) : 0.f;
      } else {
        #pragma unroll
        for (int r = 0; r < 4; r++) p[r] = fast_exp2(sc[r]);
      }
      bf16x4 pf = { (__bf16)p[0], (__bf16)p[1], (__bf16)p[2], (__bf16)p[3] };
      pfrag[kb] = pf;
      lacc = mfma16(ones4, pf, lacc);                    // l[q] partial row-sums
    }

    // PV: O^T[d][q] += V^T[d][key] P^T[key][q]; V in frag-order LDS:
    // row d = jb*16+lm, chunk cp = (2qd+h)^(lm&7) holds kb = 2h (lo 4) / 2h+1 (hi 4)
    #pragma unroll
    for (int jb = 0; jb < 4; jb++) {
      const int rowb = (jb * 16 + lm) * 64;
      const int dsw = lm & 7;
      const bf16x8 v01 = *(const bf16x8*)&Vc[rowb + ((((qd << 1) | 0) ^ dsw) << 3)];
      const bf16x8 v23 = *(const bf16x8*)&Vc[rowb + ((((qd << 1) | 1) ^ dsw) << 3)];
      bf16x4 a0 = { v01[0], v01[1], v01[2], v01[3] };
      bf16x4 a1 = { v01[4], v01[5], v01[6], v01[7] };
      bf16x4 a2 = { v23[0], v23[1], v23[2], v23[3] };
      bf16x4 a3 = { v23[4], v23[5], v23[6], v23[7] };
      o[jb] = mfma16(a0, pfrag[0], o[jb]);
      o[jb] = mfma16(a1, pfrag[1], o[jb]);
      o[jb] = mfma16(a2, pfrag[2], o[jb]);
      o[jb] = mfma16(a3, pfrag[3], o[jb]);
    }
  }

  const int b = bh >> 4, h = bh & 15;
  const float inv = 1.0f / lacc[0];
  const size_t base = ((size_t)(b * S_LEN + qglob)) * D_DIM + h * 64 + qd * 4;
  #pragma unroll
  for (int jb = 0; jb < 4; jb++) {
    bf16x4 ov = { (__bf16)(o[jb][0] * inv), (__bf16)(o[jb][1] * inv),
                  (__bf16)(o[jb][2] * inv), (__bf16)(o[jb][3] * inv) };
    *(bf16x4*)(Ob + base + jb * 16) = ov;
  }
}

extern "C" void kernel_launch(void* const* d_in, const int* in_sizes, int n_in,
                              void* d_out, int out_size, void* d_ws, size_t ws_size,
                              hipStream_t stream)
{
  (void)in_sizes; (void)n_in; (void)out_size; (void)ws_size;
  const float* x    = (const float*)d_in[0];
  const float* WQ   = (const float*)d_in[1];
  const float* WK   = (const float*)d_in[2];
  const float* WV   = (const float*)d_in[3];
  const float* WO   = (const float*)d_in[4];
  const float* gain = (const float*)d_in[5];
  const int* positions = (const int*)d_in[6];
  const int* theta     = (const int*)d_in[7];
  float* out = (float*)d_out;

  char* ws = (char*)d_ws;
  const size_t MB = 1024 * 1024;
  __bf16* xb  = (__bf16*)(ws + 0);        //  8 MB
  __bf16* WQb = (__bf16*)(ws + 8  * MB);  //  2 MB
  __bf16* WKb = (__bf16*)(ws + 10 * MB);  //  2 MB
  __bf16* WVb = (__bf16*)(ws + 12 * MB);  //  2 MB
  __bf16* WOb = (__bf16*)(ws + 14 * MB);  //  2 MB
  __bf16* Qfb = (__bf16*)(ws + 16 * MB);  //  8 MB  Q pre-norm bf16 [4096][1024]
  __bf16* Kfb = (__bf16*)(ws + 24 * MB);  //  8 MB
  __bf16* Vf  = (__bf16*)(ws + 32 * MB);  //  8 MB  [bh][kt][4096] frag-order tiles
  __bf16* Qh  = (__bf16*)(ws + 40 * MB);  //  8 MB  [bh][s][64]  (pre-scaled by SC2)
  __bf16* Kh  = (__bf16*)(ws + 48 * MB);  //  8 MB
  __bf16* Ob  = (__bf16*)(ws + 56 * MB);  //  8 MB  [b][s][1024]

  cast_all<<<1024, 256, 0, stream>>>(x, WQ, WK, WV, WO, xb, WQb, WKb, WVb, WOb);
  gemm_qkv<<<1536, 256, 0, stream>>>(xb, WQb, WKb, WVb, Qfb, Kfb, Vf);
  norm_rope<<<1024, 256, 0, stream>>>(Qfb, Kfb, gain, positions, theta, Qh, Kh);
  attn_fwd<<<1024, 256, 0, stream>>>(Qh, Kh, Vf, Ob);
  gemm_out64<<<512, 256, 0, stream>>>(Ob, WOb, out);
}

// Round 12
// 170.698 us; speedup vs baseline: 1.0387x; 1.0387x over previous
//
#include <hip/hip_runtime.h>
#include <hip/hip_bf16.h>

typedef __attribute__((ext_vector_type(8))) __bf16 bf16x8;
typedef __attribute__((ext_vector_type(4))) __bf16 bf16x4;
typedef __attribute__((ext_vector_type(4))) float  f32x4;
typedef __attribute__((ext_vector_type(4))) short  s16x4;

#define S_LEN 2048
#define D_DIM 1024
#define NH    16
#define GK    1024
#define GN    1024

__device__ __forceinline__ float fast_exp2(float x) {
#if __has_builtin(__builtin_amdgcn_exp2f)
  return __builtin_amdgcn_exp2f(x);
#else
  return exp2f(x);
#endif
}

// K=16 bf16 MFMA wrapper (builtin spelling differs across ROCm versions)
__device__ __forceinline__ f32x4 mfma16(bf16x4 a, bf16x4 b, f32x4 c) {
#if __has_builtin(__builtin_amdgcn_mfma_f32_16x16x16_bf16)
  return __builtin_amdgcn_mfma_f32_16x16x16_bf16(a, b, c, 0, 0, 0);
#else
  return __builtin_amdgcn_mfma_f32_16x16x16bf16_1k(
      __builtin_bit_cast(s16x4, a), __builtin_bit_cast(s16x4, b), c, 0, 0, 0);
#endif
}

// async global->LDS, 16B per lane; HW scatters to wave-uniform-base + lane*16
__device__ __forceinline__ void gld_lds16(const void* g, void* l) {
  __builtin_amdgcn_global_load_lds(
      (const __attribute__((address_space(1))) unsigned int*)g,
      (__attribute__((address_space(3))) unsigned int*)l, 16, 0, 0);
}

// ---------------- fused fp32 -> bf16 cast, grid-stride ----------------
__global__ __launch_bounds__(256) void cast_all(
    const float* __restrict__ x,  const float* __restrict__ wq, const float* __restrict__ wk,
    const float* __restrict__ wv, const float* __restrict__ wo,
    __bf16* __restrict__ xb, __bf16* __restrict__ wqb, __bf16* __restrict__ wkb,
    __bf16* __restrict__ wvb, __bf16* __restrict__ wob)
{
  const int NTOT = 2 << 20;                      // 2M float4 chunks
  for (int i = blockIdx.x * 256 + threadIdx.x; i < NTOT; i += 1024 * 256) {
    const float* s; __bf16* d; int off;
    if (i < (1 << 20)) { s = x; d = xb; off = i; }
    else {
      const int j = i - (1 << 20);
      const int r = j >> 18; off = j & ((1 << 18) - 1);
      s = (r == 0) ? wq : (r == 1) ? wk : (r == 2) ? wv : wo;
      d = (r == 0) ? wqb : (r == 1) ? wkb : (r == 2) ? wvb : wob;
    }
    float4 v = ((const float4*)s)[off];
    bf16x4 o = { (__bf16)v.x, (__bf16)v.y, (__bf16)v.z, (__bf16)v.w };
    ((bf16x4*)d)[off] = o;
  }
}

// ---------------- QKV GEMM 64x128, BK=64, XCD-partitioned (r0 proven) ----------
// mode 2 (V) writes LDS-order fragment layout per 64-key tile:
//   Vf[bh][kt][d][cp*8 + (kb&1)*4 + r], cp = ((ql<<1)|(kb>>1)) ^ (d&7)
//   where key = kb*16 + ql*4 + r. attn stages it LINEARLY (global src == LDS
//   order) and PV reads 2x b128 per (jb): conflict-free, contiguous per lane.
__global__ __launch_bounds__(256, 6) void gemm_qkv(
    const __bf16* __restrict__ A,
    const __bf16* __restrict__ W0, const __bf16* __restrict__ W1, const __bf16* __restrict__ W2,
    __bf16* __restrict__ C0, __bf16* __restrict__ C1, __bf16* __restrict__ VtOut)
{
  const int bid = blockIdx.x;
  const int e = bid & 7, mg = e >> 1, ng = e & 1;
  const int q = bid >> 3;              // 0..191
  const int mode = q % 3;
  const int t = q / 3;                 // 0..63
  const int m0 = (mg * 16 + (t & 15)) * 64;
  const int n0 = (ng * 4 + (t >> 4)) * 128;
  const __bf16* Wm = (mode == 0) ? W0 : (mode == 1) ? W1 : W2;

  __shared__ __align__(16) __bf16 As[64 * 64];    //  8 KB
  __shared__ __align__(16) __bf16 Bs[128 * 64];   // 16 KB

  const int tid  = threadIdx.x;
  const int lane = tid & 63;
  const int w    = tid >> 6;
  const int wr   = w >> 1, wc = w & 1;
  const int lm   = lane & 15, qd = lane >> 4;

  const __bf16* ap[2]; int loA[2];
  #pragma unroll
  for (int j = 0; j < 2; j++) {
    const int c = tid + 256 * j;
    const int r = c >> 3, cpos = c & 7;
    ap[j] = A + (size_t)(m0 + r) * GK + (cpos ^ (r & 7)) * 8;
    loA[j] = c * 8;
  }
  const __bf16* bp[4]; int loB[4];
  #pragma unroll
  for (int j = 0; j < 4; j++) {
    const int c = tid + 256 * j;
    const int r = c >> 3, cpos = c & 7;
    bp[j] = Wm + (size_t)(n0 + r) * GK + (cpos ^ (r & 7)) * 8;
    loB[j] = c * 8;
  }

  const int sw = lm & 7;

  f32x4 zero = {0.f, 0.f, 0.f, 0.f};
  f32x4 acc[2][4];
  #pragma unroll
  for (int i = 0; i < 2; i++)
    #pragma unroll
    for (int j = 0; j < 4; j++) acc[i][j] = zero;

  for (int k0 = 0; k0 < GK; k0 += 64) {
    #pragma unroll
    for (int j = 0; j < 2; j++) gld_lds16(ap[j] + k0, &As[loA[j]]);
    #pragma unroll
    for (int j = 0; j < 4; j++) gld_lds16(bp[j] + k0, &Bs[loB[j]]);
    __syncthreads();
    #pragma unroll
    for (int half = 0; half < 2; half++) {
      const int cph = ((qd + 4 * half) ^ sw) * 8;
      bf16x8 af[2], bfv[4];
      #pragma unroll
      for (int i = 0; i < 2; i++) af[i]  = *(const bf16x8*)&As[(wr * 32 + i * 16 + lm) * 64 + cph];
      #pragma unroll
      for (int j = 0; j < 4; j++) bfv[j] = *(const bf16x8*)&Bs[(wc * 64 + j * 16 + lm) * 64 + cph];
      #pragma unroll
      for (int i = 0; i < 2; i++)
        #pragma unroll
        for (int j = 0; j < 4; j++)
          acc[i][j] = __builtin_amdgcn_mfma_f32_16x16x32_bf16(af[i], bfv[j], acc[i][j], 0, 0, 0);
    }
    __syncthreads();
  }

  if (mode < 2) {
    __bf16* C = (mode == 0) ? C0 : C1;
    #pragma unroll
    for (int i = 0; i < 2; i++) {
      const int row = m0 + wr * 32 + i * 16 + qd * 4;
      #pragma unroll
      for (int j = 0; j < 4; j++) {
        const int col = n0 + wc * 64 + j * 16 + lm;
        #pragma unroll
        for (int r = 0; r < 4; r++)
          C[(size_t)(row + r) * GN + col] = (__bf16)acc[i][j][r];
      }
    }
  } else {
    #pragma unroll
    for (int i = 0; i < 2; i++) {
      const int row = m0 + wr * 32 + i * 16 + qd * 4;    // token (4 consecutive)
      const int b = row >> 11, s = row & (S_LEN - 1);
      const int kt = s >> 6;
      const int key = s & 63;                            // key&3 == 0
      const int kb = (key >> 4) & 3, ql = (key >> 2) & 3;
      #pragma unroll
      for (int j = 0; j < 4; j++) {
        const int col = n0 + wc * 64 + j * 16 + lm;      // vdim
        const int h = col >> 6, d = col & 63;
        const int cp = ((ql << 1) | (kb >> 1)) ^ (d & 7);
        bf16x4 o = { (__bf16)acc[i][j][0], (__bf16)acc[i][j][1],
                     (__bf16)acc[i][j][2], (__bf16)acc[i][j][3] };
        const size_t idx =
            (((size_t)((b * NH + h) * 32 + kt)) * 64 + d) * 64 + cp * 8 + (kb & 1) * 4;
        *(bf16x4*)(VtOut + idx) = o;
      }
    }
  }
}

// ---------------- out-proj GEMM 64x128, BK=64, XCD-partitioned (fp32 out, r0) ----
__global__ __launch_bounds__(256, 6) void gemm_out64(
    const __bf16* __restrict__ A, const __bf16* __restrict__ Wm, float* __restrict__ C)
{
  const int bid = blockIdx.x;          // 512
  const int e = bid & 7, mg = e >> 1, ng = e & 1;
  const int q = bid >> 3;              // 0..63
  const int m0 = (mg * 16 + (q & 15)) * 64;
  const int n0 = (ng * 4 + (q >> 4)) * 128;

  __shared__ __align__(16) __bf16 As[64 * 64];    //  8 KB
  __shared__ __align__(16) __bf16 Bs[128 * 64];   // 16 KB

  const int tid  = threadIdx.x;
  const int lane = tid & 63;
  const int w    = tid >> 6;
  const int wr   = w >> 1, wc = w & 1;
  const int lm   = lane & 15, qd = lane >> 4;

  const __bf16* ap[2]; int loA[2];
  #pragma unroll
  for (int j = 0; j < 2; j++) {
    const int c = tid + 256 * j;
    const int r = c >> 3, cpos = c & 7;
    ap[j] = A + (size_t)(m0 + r) * GK + (cpos ^ (r & 7)) * 8;
    loA[j] = c * 8;
  }
  const __bf16* bp[4]; int loB[4];
  #pragma unroll
  for (int j = 0; j < 4; j++) {
    const int c = tid + 256 * j;
    const int r = c >> 3, cpos = c & 7;
    bp[j] = Wm + (size_t)(n0 + r) * GK + (cpos ^ (r & 7)) * 8;
    loB[j] = c * 8;
  }

  const int sw = lm & 7;

  f32x4 zero = {0.f, 0.f, 0.f, 0.f};
  f32x4 acc[2][4];
  #pragma unroll
  for (int i = 0; i < 2; i++)
    #pragma unroll
    for (int j = 0; j < 4; j++) acc[i][j] = zero;

  for (int k0 = 0; k0 < GK; k0 += 64) {
    #pragma unroll
    for (int j = 0; j < 2; j++) gld_lds16(ap[j] + k0, &As[loA[j]]);
    #pragma unroll
    for (int j = 0; j < 4; j++) gld_lds16(bp[j] + k0, &Bs[loB[j]]);
    __syncthreads();
    #pragma unroll
    for (int half = 0; half < 2; half++) {
      const int cph = ((qd + 4 * half) ^ sw) * 8;
      bf16x8 af[2], bfv[4];
      #pragma unroll
      for (int i = 0; i < 2; i++) af[i]  = *(const bf16x8*)&As[(wr * 32 + i * 16 + lm) * 64 + cph];
      #pragma unroll
      for (int j = 0; j < 4; j++) bfv[j] = *(const bf16x8*)&Bs[(wc * 64 + j * 16 + lm) * 64 + cph];
      #pragma unroll
      for (int i = 0; i < 2; i++)
        #pragma unroll
        for (int j = 0; j < 4; j++)
          acc[i][j] = __builtin_amdgcn_mfma_f32_16x16x32_bf16(af[i], bfv[j], acc[i][j], 0, 0, 0);
    }
    __syncthreads();
  }

  #pragma unroll
  for (int i = 0; i < 2; i++) {
    const int row = m0 + wr * 32 + i * 16 + qd * 4;
    #pragma unroll
    for (int j = 0; j < 4; j++) {
      const int col = n0 + wc * 64 + j * 16 + lm;
      #pragma unroll
      for (int r = 0; r < 4; r++)
        C[(size_t)(row + r) * GN + col] = acc[i][j][r];
    }
  }
}

// ---------------- RMSNorm + RoPE + head split, wave-per-row (no LDS/barrier) -----
__global__ __launch_bounds__(256) void norm_rope(
    const __bf16* __restrict__ Qf, const __bf16* __restrict__ Kf,
    const float* __restrict__ gain, const int* __restrict__ positions,
    const int* __restrict__ theta_p,
    __bf16* __restrict__ Qh, __bf16* __restrict__ Kh)
{
  const int t = threadIdx.x;
  const int w = t >> 6, lane = t & 63;
  const int row = blockIdx.x * 4 + w;             // b*S + s
  const int s = row & (S_LEN - 1), b = row >> 11;
  const int d0 = lane * 16;

  const bf16x8 qv0 = *(const bf16x8*)(Qf + (size_t)row * D_DIM + d0);
  const bf16x8 qv1 = *(const bf16x8*)(Qf + (size_t)row * D_DIM + d0 + 8);
  const bf16x8 kv0 = *(const bf16x8*)(Kf + (size_t)row * D_DIM + d0);
  const bf16x8 kv1 = *(const bf16x8*)(Kf + (size_t)row * D_DIM + d0 + 8);

  float q[16], k[16];
  #pragma unroll
  for (int j = 0; j < 8; j++) {
    q[j] = (float)qv0[j]; q[8 + j] = (float)qv1[j];
    k[j] = (float)kv0[j]; k[8 + j] = (float)kv1[j];
  }
  float sq = 0.f, sk = 0.f;
  #pragma unroll
  for (int j = 0; j < 16; j++) { sq += q[j] * q[j]; sk += k[j] * k[j]; }
  #pragma unroll
  for (int off = 32; off; off >>= 1) { sq += __shfl_xor(sq, off); sk += __shfl_xor(sk, off); }

  const float SC2 = 0.125f * 1.44269504089f;
  const float invq = rsqrtf(sq * (1.0f / 1024.0f) + 1e-5f) * SC2;   // fold score scale
  const float invk = rsqrtf(sk * (1.0f / 1024.0f) + 1e-5f);

  float g[16];
  #pragma unroll
  for (int j = 0; j < 4; j++) {
    const float4 gv = *(const float4*)(gain + d0 + j * 4);
    g[4 * j] = gv.x; g[4 * j + 1] = gv.y; g[4 * j + 2] = gv.z; g[4 * j + 3] = gv.w;
  }

  const float pos  = (float)positions[s];
  const float lg32 = __log2f((float)theta_p[0]) * (1.0f / 32.0f);
  const int h = lane >> 2, idx0 = (lane & 3) * 16;

  bf16x8 qw0, qw1, kw0, kw1;
  #pragma unroll
  for (int pp = 0; pp < 8; pp++) {
    const int p = (lane & 3) * 8 + pp;
    const float f = fast_exp2(-(float)p * lg32);
    float sn, cs;
    __sincosf(pos * f, &sn, &cs);
    const float qe = q[2 * pp] * invq * g[2 * pp];
    const float qo = q[2 * pp + 1] * invq * g[2 * pp + 1];
    const float ke = k[2 * pp] * invk * g[2 * pp];
    const float ko = k[2 * pp + 1] * invk * g[2 * pp + 1];
    const __bf16 qre = (__bf16)(qe * cs - qo * sn);
    const __bf16 qro = (__bf16)(qo * cs + qe * sn);
    const __bf16 kre = (__bf16)(ke * cs - ko * sn);
    const __bf16 kro = (__bf16)(ko * cs + ke * sn);
    if (pp < 4) { qw0[2 * pp] = qre; qw0[2 * pp + 1] = qro;
                  kw0[2 * pp] = kre; kw0[2 * pp + 1] = kro; }
    else        { qw1[2 * (pp - 4)] = qre; qw1[2 * (pp - 4) + 1] = qro;
                  kw1[2 * (pp - 4)] = kre; kw1[2 * (pp - 4) + 1] = kro; }
  }

  const size_t obase = ((size_t)((b * NH + h) * S_LEN + s)) * 64 + idx0;
  *(bf16x8*)(Qh + obase)     = qw0;
  *(bf16x8*)(Qh + obase + 8) = qw1;
  *(bf16x8*)(Kh + obase)     = kw0;
  *(bf16x8*)(Kh + obase + 8) = kw1;
}

// ---------------- causal flash attention, S^T formulation (r10 proven) -----------
// K LDS-staged (swizzled, dbuf). V stored in LDS-fragment order by gemm_qkv:
// staging is a LINEAR 8KB copy per tile, and PV reads 2x ds_read_b128 per jb
// (conflict-free) instead of 4x ds_read_b64. Same waves, barriers, masking.
__global__ __launch_bounds__(256) void attn_fwd(
    const __bf16* __restrict__ Qh, const __bf16* __restrict__ Kh,
    const __bf16* __restrict__ Vf, __bf16* __restrict__ Ob)
{
  const int bid = blockIdx.x;
  const int g   = bid >> 5, gj = g & 7, gs = g >> 3;
  const int qt  = (gs == 0) ? 31 - gj : (gs == 1) ? gj : (gs == 2) ? 23 - gj : 8 + gj;
  const int rr  = bid & 31;
  const int bh  = (rr & 7) * 4 + (rr >> 3);      // same-bh blocks -> same bid%8 (XCD)
  const int tid = threadIdx.x, lane = tid & 63, w = tid >> 6;
  const int lm = lane & 15, qd = lane >> 4;

  __shared__ __align__(16) __bf16 smem[8192 + 8192];   // 32768 B
  __bf16* Ks = smem;                 // [2][4096]
  __bf16* Vs = smem + 8192;          // [2][4096]

  const int row0 = qt * 64 + w * 16;
  const int qglob = row0 + lm;                   // this lane's query row
  const size_t qbase = (size_t)bh * S_LEN * 64;
  const bf16x8 aq0 = *(const bf16x8*)(Qh + qbase + (size_t)qglob * 64 + qd * 8);
  const bf16x8 aq1 = *(const bf16x8*)(Qh + qbase + (size_t)qglob * 64 + 32 + qd * 8);

  const __bf16* Kb  = Kh + (size_t)bh * S_LEN * 64;
  const __bf16* Vbh = Vf + (size_t)bh * 32 * 4096;     // [kt][4096] frag-order tiles
  const int c0 = tid, c1 = 256 + tid;
  const int kr0 = c0 >> 3, kr1 = c1 >> 3;
  const int kg0 = ((c0 & 7) ^ (kr0 & 7)) * 8;
  const int kg1 = ((c1 & 7) ^ (kr1 & 7)) * 8;
  const int cpA = (qd ^ (lm & 7)) * 8;
  const int cpB = cpA ^ 32;

  auto stage = [&](int buf, int k0) {
    __bf16* Kd = Ks + buf * 4096;
    __bf16* Vd = Vs + buf * 4096;
    gld_lds16(Kb + (size_t)(k0 + kr0) * 64 + kg0, &Kd[c0 * 8]);
    gld_lds16(Kb + (size_t)(k0 + kr1) * 64 + kg1, &Kd[c1 * 8]);
    const __bf16* Vt_ = Vbh + (size_t)(k0 >> 6) * 4096;
    gld_lds16(Vt_ + c0 * 8, &Vd[c0 * 8]);
    gld_lds16(Vt_ + c1 * 8, &Vd[c1 * 8]);
  };

  f32x4 zero = {0.f, 0.f, 0.f, 0.f};
  f32x4 lacc = zero;                 // all 4 regs hold l[q=lm]
  f32x4 o[4];                        // o[jb][r] = O^T[d = jb*16+qd*4+r][q=lm]
  #pragma unroll
  for (int jb = 0; jb < 4; jb++) o[jb] = zero;

  bf16x4 ones4;
  #pragma unroll
  for (int i = 0; i < 4; i++) ones4[i] = (__bf16)1.0f;

  stage(0, 0);

  for (int kt = 0; kt <= qt; ++kt) {
    const int cur = kt & 1;
    __syncthreads();                 // buf[cur] staged; buf[cur^1] free
    if (kt < qt) stage(cur ^ 1, (kt + 1) * 64);

    const __bf16* Kc = Ks + cur * 4096;
    const __bf16* Vc = Vs + cur * 4096;
    const int k0 = kt * 64;
    const bool diag = (kt == qt);

    bf16x4 pfrag[4];
    #pragma unroll
    for (int kb = 0; kb < 4; kb++) {
      const int krow = (kb * 16 + lm) * 64;
      const bf16x8 ak0 = *(const bf16x8*)&Kc[krow + cpA];
      const bf16x8 ak1 = *(const bf16x8*)&Kc[krow + cpB];
      f32x4 sc = zero;                                   // S^T: A=K, B=Q
      sc = __builtin_amdgcn_mfma_f32_16x16x32_bf16(ak0, aq0, sc, 0, 0, 0);
      sc = __builtin_amdgcn_mfma_f32_16x16x32_bf16(ak1, aq1, sc, 0, 0, 0);
      float p[4];
      if (diag) {
        const int keyb = k0 + kb * 16 + qd * 4;
        #pragma unroll
        for (int r = 0; r < 4; r++)
          p[r] = (keyb + r <= qglob) ? fast_exp2(sc[r]) : 0.f;
      } else {
        #pragma unroll
        for (int r = 0; r < 4; r++) p[r] = fast_exp2(sc[r]);
      }
      bf16x4 pf = { (__bf16)p[0], (__bf16)p[1], (__bf16)p[2], (__bf16)p[3] };
      pfrag[kb] = pf;
      lacc = mfma16(ones4, pf, lacc);                    // l[q] partial row-sums
    }

    // PV: O^T[d][q] += V^T[d][key] P^T[key][q]; V in frag-order LDS:
    // row d = jb*16+lm, chunk cp = (2qd+h)^(lm&7) holds kb = 2h (lo 4) / 2h+1 (hi 4)
    #pragma unroll
    for (int jb = 0; jb < 4; jb++) {
      const int rowb = (jb * 16 + lm) * 64;
      const int dsw = lm & 7;
      const bf16x8 v01 = *(const bf16x8*)&Vc[rowb + ((((qd << 1) | 0) ^ dsw) << 3)];
      const bf16x8 v23 = *(const bf16x8*)&Vc[rowb + ((((qd << 1) | 1) ^ dsw) << 3)];
      bf16x4 a0 = { v01[0], v01[1], v01[2], v01[3] };
      bf16x4 a1 = { v01[4], v01[5], v01[6], v01[7] };
      bf16x4 a2 = { v23[0], v23[1], v23[2], v23[3] };
      bf16x4 a3 = { v23[4], v23[5], v23[6], v23[7] };
      o[jb] = mfma16(a0, pfrag[0], o[jb]);
      o[jb] = mfma16(a1, pfrag[1], o[jb]);
      o[jb] = mfma16(a2, pfrag[2], o[jb]);
      o[jb] = mfma16(a3, pfrag[3], o[jb]);
    }
  }

  const int b = bh >> 4, h = bh & 15;
  const float inv = 1.0f / lacc[0];
  const size_t base = ((size_t)(b * S_LEN + qglob)) * D_DIM + h * 64 + qd * 4;
  #pragma unroll
  for (int jb = 0; jb < 4; jb++) {
    bf16x4 ov = { (__bf16)(o[jb][0] * inv), (__bf16)(o[jb][1] * inv),
                  (__bf16)(o[jb][2] * inv), (__bf16)(o[jb][3] * inv) };
    *(bf16x4*)(Ob + base + jb * 16) = ov;
  }
}

extern "C" void kernel_launch(void* const* d_in, const int* in_sizes, int n_in,
                              void* d_out, int out_size, void* d_ws, size_t ws_size,
                              hipStream_t stream)
{
  (void)in_sizes; (void)n_in; (void)out_size; (void)ws_size;
  const float* x    = (const float*)d_in[0];
  const float* WQ   = (const float*)d_in[1];
  const float* WK   = (const float*)d_in[2];
  const float* WV   = (const float*)d_in[3];
  const float* WO   = (const float*)d_in[4];
  const float* gain = (const float*)d_in[5];
  const int* positions = (const int*)d_in[6];
  const int* theta     = (const int*)d_in[7];
  float* out = (float*)d_out;

  char* ws = (char*)d_ws;
  const size_t MB = 1024 * 1024;
  __bf16* xb  = (__bf16*)(ws + 0);        //  8 MB
  __bf16* WQb = (__bf16*)(ws + 8  * MB);  //  2 MB
  __bf16* WKb = (__bf16*)(ws + 10 * MB);  //  2 MB
  __bf16* WVb = (__bf16*)(ws + 12 * MB);  //  2 MB
  __bf16* WOb = (__bf16*)(ws + 14 * MB);  //  2 MB
  __bf16* Qfb = (__bf16*)(ws + 16 * MB);  //  8 MB  Q pre-norm bf16 [4096][1024]
  __bf16* Kfb = (__bf16*)(ws + 24 * MB);  //  8 MB
  __bf16* Vf  = (__bf16*)(ws + 32 * MB);  //  8 MB  [bh][kt][4096] frag-order tiles
  __bf16* Qh  = (__bf16*)(ws + 40 * MB);  //  8 MB  [bh][s][64]  (pre-scaled by SC2)
  __bf16* Kh  = (__bf16*)(ws + 48 * MB);  //  8 MB
  __bf16* Ob  = (__bf16*)(ws + 56 * MB);  //  8 MB  [b][s][1024]

  cast_all<<<1024, 256, 0, stream>>>(x, WQ, WK, WV, WO, xb, WQb, WKb, WVb, WOb);
  gemm_qkv<<<1536, 256, 0, stream>>>(xb, WQb, WKb, WVb, Qfb, Kfb, Vf);
  norm_rope<<<1024, 256, 0, stream>>>(Qfb, Kfb, gain, positions, theta, Qh, Kh);
  attn_fwd<<<1024, 256, 0, stream>>>(Qh, Kh, Vf, Ob);
  gemm_out64<<<512, 256, 0, stream>>>(Ob, WOb, out);
}